// Round 18
// baseline (185.073 us; speedup 1.0000x reference)
//
#include <hip/hip_runtime.h>

#define OFF_H 1048576
#define OFF_A 34603008
// Light barrier: orders LDS ops only; leaves global loads in flight.
#define LBAR() asm volatile("s_waitcnt lgkmcnt(0)\n\ts_barrier" ::: "memory")

typedef __fp16 h2v __attribute__((ext_vector_type(2)));
typedef _Float16 f16x8 __attribute__((ext_vector_type(8)));
typedef float f32x4 __attribute__((ext_vector_type(4)));

__global__ __launch_bounds__(1024, 4) void egt_mfma3(
    const float* __restrict__ QKV, const float* __restrict__ E,
    const float* __restrict__ G, float* __restrict__ out)
{
  // Phase-overlaid LDS (74 KB), 64-m periods:
  //  phase 1: klds [0..10495] dw, sct [10496..18943] dw
  //  phase 2: vl16 [0..9215] dw, al16 [9216..13823] dw, fin [13824..13967] dw
  __shared__ __align__(16) unsigned smem[18944];
  h2v*    klds = (h2v*)smem;               // [64 m][164]: 8h x 20dp + 4 pad
  float*  sct  = (float*)(smem + 10496);   // [8 h][16 l][66]
  __fp16* vl16 = (__fp16*)smem;            // [8 h][32 d][72]
  __fp16* al16 = (__fp16*)(smem + 9216);   // [8 h][16 l][72]
  float*  fin  = (float*)(smem + 13824);   // [16 l][9]

  const int t    = threadIdx.x;
  const int lane = t & 63;
  const int wv   = t >> 6;                 // 16 waves
  const int h    = wv & 7, mh = wv >> 3;   // mfma domain: (head, m/d half)
  const int g    = lane >> 4, c = lane & 15;
  const int cl   = wv;                     // coalesced domain: l row
  const int cu   = lane;                   // m-chunk (64 per period)
  const int sm   = t >> 4, sch = t & 15;   // staging: m-row 0..63, 16-float chunk
  const int b    = blockIdx.x >> 6;
  const int l0   = (blockIdx.x & 63) << 4;
  const size_t qb = (size_t)b * 786432;
  const size_t erow = (size_t)(b*1024 + l0 + cl) * 8192 + cu*8;

  // ---- Q fragment: qf[j] = Q[l0+c][d=8g+j], head h ----
  f16x8 qf;
  {
    const float* qp = QKV + qb + (size_t)(l0 + c)*768 + g*64 + h;
    #pragma unroll
    for (int p2 = 0; p2 < 4; p2++)
      ((h2v*)&qf)[p2] = __builtin_amdgcn_cvt_pkrtz(qp[p2*16], qp[p2*16+8]);
  }

  float esum[8] = {0.f,0.f,0.f,0.f,0.f,0.f,0.f,0.f};
  float4 e4[2][2], k4[4];

  // ---- phase-1 prologue: K(0)->klds, K(1)+E(0),E(1) in flight ----
  {
    const float* ks = QKV + qb + (size_t)sm*768 + 256 + sch*16;
    #pragma unroll
    for (int i = 0; i < 4; i++) k4[i] = *(const float4*)(ks + i*4);
    e4[0][0] = *(const float4*)&E[erow];
    e4[0][1] = *(const float4*)&E[erow + 4];
    e4[1][0] = *(const float4*)&E[erow + 512];
    e4[1][1] = *(const float4*)&E[erow + 516];
    const float* kf_ = (const float*)k4;
    #pragma unroll
    for (int j = 0; j < 8; j++)
      klds[sm*164 + j*20 + sch] = __builtin_amdgcn_cvt_pkrtz(kf_[j], kf_[j+8]);
    const float* ks1 = QKV + qb + (size_t)(64 + sm)*768 + 256 + sch*16;
    #pragma unroll
    for (int i = 0; i < 4; i++) k4[i] = *(const float4*)(ks1 + i*4);
  }
  __syncthreads();

  // ================= PHASE 1 (16 periods x 64 m) =================
  for (int p = 0; p < 16; p++){
    // A: QK mfma for this wave's 32-m half -> sct
    #pragma unroll
    for (int sub = 0; sub < 2; sub++){
      const int mrow = mh*32 + sub*16 + c;
      f16x8 kf = *(const f16x8*)&klds[mrow*164 + h*20 + 4*g];
      f32x4 z = {0.f,0.f,0.f,0.f};
      f32x4 s = __builtin_amdgcn_mfma_f32_16x16x32_f16(qf, kf, z, 0, 0, 0);
      #pragma unroll
      for (int r = 0; r < 4; r++)
        sct[h*1056 + (4*g+r)*66 + mh*32 + sub*16 + c] = s[r];
    }
    LBAR();
    // B: stage K(p+1); issue K(p+2); coalesced elementwise
    if (p+1 < 16){
      const float* kf_ = (const float*)k4;
      #pragma unroll
      for (int j = 0; j < 8; j++)
        klds[sm*164 + j*20 + sch] = __builtin_amdgcn_cvt_pkrtz(kf_[j], kf_[j+8]);
    }
    if (p+2 < 16){
      const float* ks = QKV + qb + (size_t)((p+2)*64 + sm)*768 + 256 + sch*16;
      #pragma unroll
      for (int i = 0; i < 4; i++) k4[i] = *(const float4*)(ks + i*4);
    }
    {
      float ev[8], hv[8];
      *(float4*)&ev[0] = e4[p&1][0];
      *(float4*)&ev[4] = e4[p&1][1];
      if (p+2 < 16){
        e4[p&1][0] = *(const float4*)&E[erow + (size_t)(p+2)*512];
        e4[p&1][1] = *(const float4*)&E[erow + (size_t)(p+2)*512 + 4];
      }
      #pragma unroll
      for (int hh = 0; hh < 8; hh++){
        float s = sct[hh*1056 + cl*66 + cu];
        float x = fminf(fmaxf(s, -5.f), 5.f) + ev[hh];
        hv[hh] = x;
        esum[hh] += __expf(x);
      }
      *(float4*)&out[OFF_H + erow + (size_t)p*512]     = *(float4*)&hv[0];
      *(float4*)&out[OFF_H + erow + (size_t)p*512 + 4] = *(float4*)&hv[4];
    }
    LBAR();
  }

  // ---- expsum reduce over the 64 lanes (all m) of wave cl ----
  float rcp8[8];
  #pragma unroll
  for (int hh = 0; hh < 8; hh++){
    float v = esum[hh];
    v += __shfl_xor(v, 1); v += __shfl_xor(v, 2); v += __shfl_xor(v, 4);
    v += __shfl_xor(v, 8); v += __shfl_xor(v, 16); v += __shfl_xor(v, 32);
    rcp8[hh] = 1.f / v;
  }

  // ================= PHASE 2 (16 periods x 64 m) =================
  float dsum[8] = {0.f,0.f,0.f,0.f,0.f,0.f,0.f,0.f};
  f32x4 vc = {0.f,0.f,0.f,0.f};
  float4 v4[4], g4[2], h4[2];
  {
    const float* vs = QKV + qb + (size_t)sm*768 + 512 + sch*16;
    #pragma unroll
    for (int i = 0; i < 4; i++) v4[i] = *(const float4*)(vs + i*4);
    g4[0] = *(const float4*)&G[erow];
    g4[1] = *(const float4*)&G[erow + 4];
    h4[0] = *(const float4*)&out[OFF_H + erow];
    h4[1] = *(const float4*)&out[OFF_H + erow + 4];
  }
  __syncthreads();

  for (int p = 0; p < 16; p++){
    // A: V(p)->vl16; elementwise A(p)->al16+global; issue p+1 loads
    {
      const float* vf_ = (const float*)v4;
      #pragma unroll
      for (int j = 0; j < 16; j++){
        int d = 2*sch + (j>>3), hh = j&7;
        vl16[hh*2304 + d*72 + sm] = (__fp16)vf_[j];
      }
      if (p+1 < 16){
        const float* vs = QKV + qb + (size_t)((p+1)*64 + sm)*768 + 512 + sch*16;
        #pragma unroll
        for (int i = 0; i < 4; i++) v4[i] = *(const float4*)(vs + i*4);
      }
      float gv[8], hvv[8], av[8];
      *(float4*)&gv[0]  = g4[0]; *(float4*)&gv[4]  = g4[1];
      *(float4*)&hvv[0] = h4[0]; *(float4*)&hvv[4] = h4[1];
      if (p+1 < 16){
        g4[0] = *(const float4*)&G[erow + (size_t)(p+1)*512];
        g4[1] = *(const float4*)&G[erow + (size_t)(p+1)*512 + 4];
        h4[0] = *(const float4*)&out[OFF_H + erow + (size_t)(p+1)*512];
        h4[1] = *(const float4*)&out[OFF_H + erow + (size_t)(p+1)*512 + 4];
      }
      #pragma unroll
      for (int hh = 0; hh < 8; hh++){
        float sig = 1.f / (1.f + __expf(-gv[hh]));
        float A = __expf(hvv[hh]) * rcp8[hh] * sig;
        dsum[hh] += sig;
        av[hh] = A;
        al16[hh*1152 + cl*72 + cu] = (__fp16)A;
      }
      *(float4*)&out[OFF_A + erow + (size_t)p*512]     = *(float4*)&av[0];
      *(float4*)&out[OFF_A + erow + (size_t)p*512 + 4] = *(float4*)&av[4];
    }
    LBAR();
    // B: PV mfma — wave owns d-half mh, accumulates both k-halves
    #pragma unroll
    for (int kh = 0; kh < 2; kh++){
      f16x8 af = *(const f16x8*)&al16[h*1152 + c*72 + kh*32 + 8*g];
      f16x8 vf = *(const f16x8*)&vl16[h*2304 + (mh*16 + c)*72 + kh*32 + 8*g];
      vc = __builtin_amdgcn_mfma_f32_16x16x32_f16(af, vf, vc, 0, 0, 0);
    }
    LBAR();
  }

  // ---- degrees reduce; scalers to LDS ----
  #pragma unroll
  for (int hh = 0; hh < 8; hh++){
    float v = dsum[hh];
    v += __shfl_xor(v, 1); v += __shfl_xor(v, 2); v += __shfl_xor(v, 4);
    v += __shfl_xor(v, 8); v += __shfl_xor(v, 16); v += __shfl_xor(v, 32);
    dsum[hh] = v;
  }
  if (cu == 0){
    #pragma unroll
    for (int hh = 0; hh < 8; hh++) fin[cl*9 + hh] = log1pf(dsum[hh]);
  }
  __syncthreads();

  // ---- V_att store (mfma domain): wave (mh,h) owns d-half mh ----
  #pragma unroll
  for (int r = 0; r < 4; r++){
    float scl = fin[(4*g+r)*9 + h];
    const int ob = (b*1024 + l0 + 4*g + r)*256 + h;
    out[ob + (mh*16 + c)*8] = vc[r] * scl;
  }
}

extern "C" void kernel_launch(void* const* d_in, const int* in_sizes, int n_in,
                              void* d_out, int out_size, void* d_ws, size_t ws_size,
                              hipStream_t stream) {
  const float* QKV = (const float*)d_in[0];
  const float* E   = (const float*)d_in[1];
  const float* G   = (const float*)d_in[2];
  float* out = (float*)d_out;
  egt_mfma3<<<dim3(256), 1024, 0, stream>>>(QKV, E, G, out);
}

// Round 19
// 170.618 us; speedup vs baseline: 1.0847x; 1.0847x over previous
//
#include <hip/hip_runtime.h>

#define OFF_H 1048576
#define OFF_A 34603008
#define ES_OFF 0
#define DG_OFF 65536
#define V_OFF  131072
// Light barrier: orders LDS ops only; leaves global loads in flight.
#define LBAR() asm volatile("s_waitcnt lgkmcnt(0)\n\ts_barrier" ::: "memory")

typedef __fp16 h2v __attribute__((ext_vector_type(2)));
typedef _Float16 f16x8 __attribute__((ext_vector_type(8)));
typedef float f32x4 __attribute__((ext_vector_type(4)));

// ===== Kernel A: H_hat = clip(QK^T)+E over m in [M0,M0+512); partial expsum -> ws =====
__global__ __launch_bounds__(512, 4) void egt_a(
    const float* __restrict__ QKV, const float* __restrict__ E,
    float* __restrict__ out, float* __restrict__ ws)
{
  __shared__ __align__(16) h2v   klds[5248];   // K: [m32][164]
  __shared__ __align__(16) float sct[4224];    // scores: [h8][l16][33]

  const int t    = threadIdx.x;
  const int lane = t & 63;
  const int wv   = t >> 6;
  const int g    = lane >> 4, c = lane & 15;
  const int cl   = t >> 5,  cu = t & 31;
  const int sm   = t >> 4,  sch = t & 15;
  const int bid  = blockIdx.x;
  const int b    = bid >> 7, lt = (bid >> 1) & 63, mh = bid & 1;
  const int l0   = lt << 4;
  const int M0   = mh << 9;
  const size_t qb = (size_t)b * 786432;
  const size_t erow = (size_t)(b*1024 + l0 + cl) * 8192 + (size_t)M0*8 + cu*8;

  f16x8 qf;
  {
    const float* qp = QKV + qb + (size_t)(l0 + c)*768 + g*64 + wv;
    #pragma unroll
    for (int p2 = 0; p2 < 4; p2++)
      ((h2v*)&qf)[p2] = __builtin_amdgcn_cvt_pkrtz(qp[p2*16], qp[p2*16+8]);
  }

  float esum[8] = {0.f,0.f,0.f,0.f,0.f,0.f,0.f,0.f};
  float4 e4[2][2], k4[4];

  {
    const float* ks = QKV + qb + (size_t)(M0 + sm)*768 + 256 + sch*16;
    #pragma unroll
    for (int i = 0; i < 4; i++) k4[i] = *(const float4*)(ks + i*4);
    e4[0][0] = *(const float4*)&E[erow];
    e4[0][1] = *(const float4*)&E[erow + 4];
    e4[1][0] = *(const float4*)&E[erow + 256];
    e4[1][1] = *(const float4*)&E[erow + 260];
    const float* kf_ = (const float*)k4;
    #pragma unroll
    for (int j = 0; j < 8; j++)
      klds[sm*164 + j*20 + sch] = __builtin_amdgcn_cvt_pkrtz(kf_[j], kf_[j+8]);
    const float* ks1 = QKV + qb + (size_t)(M0 + 32 + sm)*768 + 256 + sch*16;
    #pragma unroll
    for (int i = 0; i < 4; i++) k4[i] = *(const float4*)(ks1 + i*4);
  }
  __syncthreads();

  #pragma unroll 2
  for (int p = 0; p < 16; p++){
    #pragma unroll
    for (int sub = 0; sub < 2; sub++){
      f16x8 kf = *(const f16x8*)&klds[(sub*16 + c)*164 + wv*20 + 4*g];
      f32x4 z = {0.f,0.f,0.f,0.f};
      f32x4 s = __builtin_amdgcn_mfma_f32_16x16x32_f16(qf, kf, z, 0, 0, 0);
      #pragma unroll
      for (int r = 0; r < 4; r++)
        sct[wv*528 + (4*g+r)*33 + sub*16 + c] = s[r];
    }
    LBAR();
    if (p+1 < 16){
      const float* kf_ = (const float*)k4;
      #pragma unroll
      for (int j = 0; j < 8; j++)
        klds[sm*164 + j*20 + sch] = __builtin_amdgcn_cvt_pkrtz(kf_[j], kf_[j+8]);
    }
    if (p+2 < 16){
      const float* ks = QKV + qb + (size_t)(M0 + (p+2)*32 + sm)*768 + 256 + sch*16;
      #pragma unroll
      for (int i = 0; i < 4; i++) k4[i] = *(const float4*)(ks + i*4);
    }
    {
      float ev[8], hv[8];
      *(float4*)&ev[0] = e4[p&1][0];
      *(float4*)&ev[4] = e4[p&1][1];
      if (p+2 < 16){
        e4[p&1][0] = *(const float4*)&E[erow + (size_t)(p+2)*256];
        e4[p&1][1] = *(const float4*)&E[erow + (size_t)(p+2)*256 + 4];
      }
      #pragma unroll
      for (int hh = 0; hh < 8; hh++){
        float s = sct[hh*528 + cl*33 + cu];
        float x = fminf(fmaxf(s, -5.f), 5.f) + ev[hh];
        hv[hh] = x;
        esum[hh] += __expf(x);
      }
      *(float4*)&out[OFF_H + erow + (size_t)p*256]     = *(float4*)&hv[0];
      *(float4*)&out[OFF_H + erow + (size_t)p*256 + 4] = *(float4*)&hv[4];
    }
    LBAR();
  }

  #pragma unroll
  for (int hh = 0; hh < 8; hh++){
    float v = esum[hh];
    v += __shfl_xor(v, 1); v += __shfl_xor(v, 2); v += __shfl_xor(v, 4);
    v += __shfl_xor(v, 8); v += __shfl_xor(v, 16);
    esum[hh] = v;
  }
  if (cu == 0){
    const int row = b*1024 + l0 + cl;
    #pragma unroll
    for (int hh = 0; hh < 8; hh++)
      ws[ES_OFF + row*16 + mh*8 + hh] = esum[hh];
  }
}

// ===== Kernel B: A_tild + partial degrees + partial PV over m in [M0,M0+512) =====
__global__ __launch_bounds__(512, 4) void egt_b(
    const float* __restrict__ QKV, const float* __restrict__ G,
    float* __restrict__ out, float* __restrict__ ws)
{
  __shared__ __align__(16) __fp16 vl16[10240]; // V^T: [h8][d32][40]
  __shared__ __align__(16) __fp16 al16[5120];  // A: [h8][l16][40]

  const int t    = threadIdx.x;
  const int lane = t & 63;
  const int wv   = t >> 6;
  const int g    = lane >> 4, c = lane & 15;
  const int cl   = t >> 5,  cu = t & 31;
  const int sm   = t >> 4,  sch = t & 15;
  const int bid  = blockIdx.x;
  const int b    = bid >> 7, lt = (bid >> 1) & 63, mh = bid & 1;
  const int l0   = lt << 4;
  const int M0   = mh << 9;
  const size_t qb = (size_t)b * 786432;
  const int row  = b*1024 + l0 + cl;
  const size_t erow = (size_t)row * 8192 + (size_t)M0*8 + cu*8;

  float rcp8[8];
  #pragma unroll
  for (int hh = 0; hh < 8; hh++)
    rcp8[hh] = 1.f / (ws[ES_OFF + row*16 + hh] + ws[ES_OFF + row*16 + 8 + hh]);

  float dsum[8] = {0.f,0.f,0.f,0.f,0.f,0.f,0.f,0.f};
  f32x4 vc0 = {0.f,0.f,0.f,0.f}, vc1 = {0.f,0.f,0.f,0.f};
  float4 v4[4], g4[2], h4[2];
  {
    const float* vs = QKV + qb + (size_t)(M0 + sm)*768 + 512 + sch*16;
    #pragma unroll
    for (int i = 0; i < 4; i++) v4[i] = *(const float4*)(vs + i*4);
    g4[0] = *(const float4*)&G[erow];
    g4[1] = *(const float4*)&G[erow + 4];
    h4[0] = *(const float4*)&out[OFF_H + erow];
    h4[1] = *(const float4*)&out[OFF_H + erow + 4];
  }
  __syncthreads();

  #pragma unroll 2
  for (int p = 0; p < 16; p++){
    {
      const float* vf_ = (const float*)v4;
      #pragma unroll
      for (int j = 0; j < 16; j++){
        int d = 2*sch + (j>>3), hh = j&7;
        vl16[hh*1280 + d*40 + sm] = (__fp16)vf_[j];
      }
      if (p+1 < 16){
        const float* vs = QKV + qb + (size_t)(M0 + (p+1)*32 + sm)*768 + 512 + sch*16;
        #pragma unroll
        for (int i = 0; i < 4; i++) v4[i] = *(const float4*)(vs + i*4);
      }
      float gv[8], hvv[8], av[8];
      *(float4*)&gv[0]  = g4[0]; *(float4*)&gv[4]  = g4[1];
      *(float4*)&hvv[0] = h4[0]; *(float4*)&hvv[4] = h4[1];
      if (p+1 < 16){
        g4[0] = *(const float4*)&G[erow + (size_t)(p+1)*256];
        g4[1] = *(const float4*)&G[erow + (size_t)(p+1)*256 + 4];
        h4[0] = *(const float4*)&out[OFF_H + erow + (size_t)(p+1)*256];
        h4[1] = *(const float4*)&out[OFF_H + erow + (size_t)(p+1)*256 + 4];
      }
      #pragma unroll
      for (int hh = 0; hh < 8; hh++){
        float sig = 1.f / (1.f + __expf(-gv[hh]));
        float A = __expf(hvv[hh]) * rcp8[hh] * sig;
        dsum[hh] += sig;
        av[hh] = A;
        al16[hh*640 + cl*40 + cu] = (__fp16)A;
      }
      *(float4*)&out[OFF_A + erow + (size_t)p*256]     = *(float4*)&av[0];
      *(float4*)&out[OFF_A + erow + (size_t)p*256 + 4] = *(float4*)&av[4];
    }
    LBAR();
    {
      f16x8 af  = *(const f16x8*)&al16[wv*640 + c*40 + 8*g];
      f16x8 vf0 = *(const f16x8*)&vl16[wv*1280 + c*40 + 8*g];
      f16x8 vf1 = *(const f16x8*)&vl16[wv*1280 + (c+16)*40 + 8*g];
      vc0 = __builtin_amdgcn_mfma_f32_16x16x32_f16(af, vf0, vc0, 0, 0, 0);
      vc1 = __builtin_amdgcn_mfma_f32_16x16x32_f16(af, vf1, vc1, 0, 0, 0);
    }
    LBAR();
  }

  #pragma unroll
  for (int hh = 0; hh < 8; hh++){
    float v = dsum[hh];
    v += __shfl_xor(v, 1); v += __shfl_xor(v, 2); v += __shfl_xor(v, 4);
    v += __shfl_xor(v, 8); v += __shfl_xor(v, 16);
    dsum[hh] = v;
  }
  if (cu == 0){
    #pragma unroll
    for (int hh = 0; hh < 8; hh++)
      ws[DG_OFF + row*16 + mh*8 + hh] = dsum[hh];
  }

  // partial V_att (unscaled): mh=0 -> out, mh=1 -> ws
  #pragma unroll
  for (int r = 0; r < 4; r++){
    const int ob = (b*1024 + l0 + 4*g + r)*256 + wv;
    if (mh == 0){
      out[ob + c*8]      = vc0[r];
      out[ob + (c+16)*8] = vc1[r];
    } else {
      ws[V_OFF + ob + c*8]      = vc0[r];
      ws[V_OFF + ob + (c+16)*8] = vc1[r];
    }
  }
}

// ===== Kernel C: combine partials, scale by log1p(degrees) =====
__global__ __launch_bounds__(256, 8) void egt_c(
    float* __restrict__ out, const float* __restrict__ ws)
{
  const int idx = (blockIdx.x * 256 + threadIdx.x) * 4;
  const int row = idx >> 8;
  const int cb  = idx & 255;
  float4 a  = *(const float4*)&out[idx];
  float4 bv = *(const float4*)&ws[V_OFF + idx];
  float o[4];
  #pragma unroll
  for (int j = 0; j < 4; j++){
    const int h = (cb + j) & 7;
    float dsc = log1pf(ws[DG_OFF + row*16 + h] + ws[DG_OFF + row*16 + 8 + h]);
    o[j] = (((const float*)&a)[j] + ((const float*)&bv)[j]) * dsc;
  }
  *(float4*)&out[idx] = *(const float4*)&o[0];
}

extern "C" void kernel_launch(void* const* d_in, const int* in_sizes, int n_in,
                              void* d_out, int out_size, void* d_ws, size_t ws_size,
                              hipStream_t stream) {
  const float* QKV = (const float*)d_in[0];
  const float* E   = (const float*)d_in[1];
  const float* G   = (const float*)d_in[2];
  float* out = (float*)d_out;
  float* ws  = (float*)d_ws;
  egt_a<<<dim3(512), 512, 0, stream>>>(QKV, E, out, ws);
  egt_b<<<dim3(512), 512, 0, stream>>>(QKV, G, out, ws);
  egt_c<<<dim3(1024), 256, 0, stream>>>(out, ws);
}